// Round 1
// baseline (8296.440 us; speedup 1.0000x reference)
//
#include <hip/hip_runtime.h>
#include <stdint.h>

#define BB 512
#define TT 512
#define FF 128
#define UU 256

typedef float f32x4 __attribute__((ext_vector_type(4)));
typedef short short8 __attribute__((ext_vector_type(8)));
typedef float float4v __attribute__((ext_vector_type(4)));

__device__ __forceinline__ unsigned short f2bf(float f) {
  union { float f; uint32_t u; } v; v.f = f;
  uint32_t u = v.u;
  u += 0x7fffu + ((u >> 16) & 1u);
  return (unsigned short)(u >> 16);
}

__device__ __forceinline__ float fast_rcp(float x) { return __builtin_amdgcn_rcpf(x); }
__device__ __forceinline__ float sigmoidf_(float x) { return fast_rcp(1.f + __expf(-x)); }
__device__ __forceinline__ float tanhf_(float x) { return 1.f - 2.f * fast_rcp(1.f + __expf(2.f * x)); }

// Build W^T (combined [Wx;Wh]) as [1024 cols][384 k] bf16, Wo^T as [32][256] bf16, zero flags.
__global__ void prep_weights(const float* __restrict__ Wx, const float* __restrict__ Wh,
                             const float* __restrict__ Wo,
                             unsigned short* __restrict__ Wt, unsigned short* __restrict__ Wot,
                             int* __restrict__ flags) {
  int bidx = blockIdx.x;
  int tid = threadIdx.x; // 384 threads
  if (bidx < 1024) {
    int n = bidx, k = tid;
    float v = (k < FF) ? Wx[(size_t)k * 1024 + n] : Wh[(size_t)(k - FF) * 1024 + n];
    Wt[(size_t)n * 384 + k] = f2bf(v);
  } else if (bidx == 1024) {
    for (int i = tid; i < 32 * 256; i += 384) {
      int o = i >> 8, u = i & 255;
      Wot[o * 256 + u] = f2bf(Wo[(size_t)u * 32 + o]);
    }
  } else {
    for (int i = tid; i < 64 * 32; i += 384) flags[i] = 0;
  }
}

// 64 blocks x 512 threads. Block bid: m-tile = bid&31 (16 batch rows), half = bid>>5 (128 of 256 units).
// Each wave (8 per WG) owns 16 units x 4 gates. B-fragments register-resident for all 512 steps.
__global__ void __launch_bounds__(512, 2)
lstm_main(const float* __restrict__ x, const unsigned short* __restrict__ Wt,
          const float* __restrict__ bvec, unsigned short* __restrict__ h_hist,
          int* flags) {
  const int bid = blockIdx.x;
  const int mt = bid & 31, half = bid >> 5;
  const int partner = bid ^ 32;
  const int tid = threadIdx.x;
  const int w = tid >> 6, l = tid & 63;
  const int lr = l & 15, lhi = l >> 4;
  const int b0 = mt * 16;
  const int uloc = half * 128 + w * 16 + lr;  // unit index in [0,256)

  // Register-resident B fragments: Bf[gate][k-frag], k-frags 0..3 = x (F=128), 4..11 = h (U=256).
  short8 Bf[4][12];
#pragma unroll
  for (int g = 0; g < 4; ++g) {
    const unsigned short* wp = Wt + (size_t)(g * 256 + uloc) * 384 + 8 * lhi;
#pragma unroll
    for (int k = 0; k < 12; ++k)
      Bf[g][k] = *(const short8*)(wp + k * 32);
  }
  float bias[4];
#pragma unroll
  for (int g = 0; g < 4; ++g) bias[g] = bvec[g * 256 + uloc];

  float cst[4] = {0.f, 0.f, 0.f, 0.f};  // c-state: rows 4*lhi+r, col uloc

  const int ko_own = 4 + half * 4;
  const int ko_par = 4 + (1 - half) * 4;
  const int kh_own = half * 128;
  const int kh_par = (1 - half) * 128;

#pragma unroll 1
  for (int t = 0; t < TT; ++t) {
    f32x4 acc[4];
#pragma unroll
    for (int g = 0; g < 4; ++g) {
      f32x4 a4 = {bias[g], bias[g], bias[g], bias[g]};
      acc[g] = a4;
    }

    // x part (k-frags 0..3), f32 -> bf16 on the fly
    const float* xp = x + ((size_t)(b0 + lr) * TT + t) * FF + 8 * lhi;
#pragma unroll
    for (int kk = 0; kk < 4; ++kk) {
      float4v lo = *(const float4v*)(xp + kk * 32);
      float4v hi = *(const float4v*)(xp + kk * 32 + 4);
      union { short8 v; unsigned short s[8]; } a;
      a.s[0] = f2bf(lo.x); a.s[1] = f2bf(lo.y); a.s[2] = f2bf(lo.z); a.s[3] = f2bf(lo.w);
      a.s[4] = f2bf(hi.x); a.s[5] = f2bf(hi.y); a.s[6] = f2bf(hi.z); a.s[7] = f2bf(hi.w);
#pragma unroll
      for (int g = 0; g < 4; ++g)
        acc[g] = __builtin_amdgcn_mfma_f32_16x16x32_bf16(a.v, Bf[g][kk], acc[g], 0, 0, 0);
    }

    if (t > 0) {
      const unsigned short* hp =
          h_hist + (size_t)t * (BB * UU) + (size_t)(b0 + lr) * UU + 8 * lhi;
      // own half (written by this WG last step; __syncthreads ordered)
#pragma unroll
      for (int ko = 0; ko < 4; ++ko) {
        short8 a = *(const short8*)(hp + kh_own + ko * 32);
#pragma unroll
        for (int g = 0; g < 4; ++g)
          acc[g] = __builtin_amdgcn_mfma_f32_16x16x32_bf16(a, Bf[g][ko_own + ko], acc[g], 0, 0, 0);
      }
      // wait for partner half of h(t)
      while (__hip_atomic_load(&flags[partner * 32], __ATOMIC_ACQUIRE,
                               __HIP_MEMORY_SCOPE_AGENT) < t) {}
#pragma unroll
      for (int ko = 0; ko < 4; ++ko) {
        short8 a = *(const short8*)(hp + kh_par + ko * 32);
#pragma unroll
        for (int g = 0; g < 4; ++g)
          acc[g] = __builtin_amdgcn_mfma_f32_16x16x32_bf16(a, Bf[g][ko_par + ko], acc[g], 0, 0, 0);
      }
    }

    // gate combine: thread holds i,f,g,o for (rows 4*lhi+r, unit uloc)
    unsigned short hs[4];
#pragma unroll
    for (int r = 0; r < 4; ++r) {
      float zi = acc[0][r], zf = acc[1][r], zg = acc[2][r], zo = acc[3][r];
      float si = sigmoidf_(zi), sf = sigmoidf_(zf), so = sigmoidf_(zo);
      float tg = tanhf_(zg);
      float cn = sf * cst[r] + si * tg;
      cst[r] = cn;
      hs[r] = f2bf(so * tanhf_(cn));
    }
    unsigned short* hw = h_hist + (size_t)(t + 1) * (BB * UU) + uloc;
#pragma unroll
    for (int r = 0; r < 4; ++r)
      hw[(size_t)(b0 + 4 * lhi + r) * UU] = hs[r];

    __syncthreads();
    if (tid == 0) {
      __threadfence();
      __hip_atomic_store(&flags[bid * 32], t + 1, __ATOMIC_RELEASE, __HIP_MEMORY_SCOPE_AGENT);
    }
  }
}

// y[b][t][:] = h(t+1) @ Wo + bo, one wave per (b, 16-step t-tile)
__global__ void __launch_bounds__(256)
y_gemm(const unsigned short* __restrict__ h_hist, const unsigned short* __restrict__ Wot,
       const float* __restrict__ bo, float* __restrict__ out) {
  int gw = (int)((blockIdx.x * 256 + threadIdx.x) >> 6);  // 0..16383
  int l = threadIdx.x & 63;
  int lr = l & 15, lhi = l >> 4;
  int b = gw >> 5;
  int t0 = (gw & 31) * 16;

  short8 Wf[2][8];
#pragma unroll
  for (int n = 0; n < 2; ++n) {
    const unsigned short* wp = Wot + (n * 16 + lr) * 256 + 8 * lhi;
#pragma unroll
    for (int kk = 0; kk < 8; ++kk) Wf[n][kk] = *(const short8*)(wp + kk * 32);
  }
  f32x4 acc[2];
#pragma unroll
  for (int n = 0; n < 2; ++n) {
    float bb = bo[n * 16 + lr];
    f32x4 a4 = {bb, bb, bb, bb};
    acc[n] = a4;
  }
  const unsigned short* hp =
      h_hist + ((size_t)(t0 + lr + 1) * BB + b) * UU + 8 * lhi;
#pragma unroll
  for (int kk = 0; kk < 8; ++kk) {
    short8 a = *(const short8*)(hp + kk * 32);
#pragma unroll
    for (int n = 0; n < 2; ++n)
      acc[n] = __builtin_amdgcn_mfma_f32_16x16x32_bf16(a, Wf[n][kk], acc[n], 0, 0, 0);
  }
#pragma unroll
  for (int n = 0; n < 2; ++n) {
    int o = n * 16 + lr;
#pragma unroll
    for (int r = 0; r < 4; ++r) {
      int t = t0 + 4 * lhi + r;
      out[((size_t)b * TT + t) * 32 + o] = acc[n][r];
    }
  }
}

extern "C" void kernel_launch(void* const* d_in, const int* in_sizes, int n_in,
                              void* d_out, int out_size, void* d_ws, size_t ws_size,
                              hipStream_t stream) {
  const float* x  = (const float*)d_in[0];
  const float* Wx = (const float*)d_in[1];
  const float* Wh = (const float*)d_in[2];
  const float* bv = (const float*)d_in[3];
  const float* Wo = (const float*)d_in[4];
  const float* bo = (const float*)d_in[5];
  // d_in[6] = seq_lengths: unused by the returned math (per reference docstring)

  char* ws = (char*)d_ws;
  unsigned short* h_hist = (unsigned short*)ws;                    // 513 * 512 * 256 * 2 B
  size_t off = (size_t)513 * BB * UU * 2;
  unsigned short* Wt = (unsigned short*)(ws + off); off += (size_t)1024 * 384 * 2;
  unsigned short* Wot = (unsigned short*)(ws + off); off += (size_t)32 * 256 * 2;
  int* flags = (int*)(ws + off); off += (size_t)64 * 32 * 4;

  prep_weights<<<1026, 384, 0, stream>>>(Wx, Wh, Wo, Wt, Wot, flags);
  lstm_main<<<64, 512, 0, stream>>>(x, Wt, bv, h_hist, flags);
  y_gemm<<<4096, 256, 0, stream>>>(h_hist, Wot, bo, (float*)d_out);
}